// Round 1
// baseline (257.800 us; speedup 1.0000x reference)
//
#include <hip/hip_runtime.h>
#include <hip/hip_bf16.h>

#define N_NODES 100000
#define N_EDGES 3200000
#define IN_F 256
#define OUT_F 128

typedef __attribute__((ext_vector_type(8))) short bf16x8;
typedef __attribute__((ext_vector_type(4))) float f32x4;

__device__ __forceinline__ unsigned short f2bf(float f) {
    unsigned int u = __float_as_uint(f);
    u += 0x7fffu + ((u >> 16) & 1u);   // round-to-nearest-even
    return (unsigned short)(u >> 16);
}

// ---- Kernel 0: W [256][128] f32 -> Wt [128][256] bf16 (transpose+convert) ----
__global__ void k_wt(const float* __restrict__ W, unsigned short* __restrict__ Wt) {
    int idx = blockIdx.x * 256 + threadIdx.x;
    if (idx >= IN_F * OUT_F) return;
    int k = idx >> 7;          // 0..255
    int c = idx & 127;         // 0..127
    Wt[c * IN_F + k] = f2bf(W[idx]);
}

// ---- Kernel 1: CSR row_ptr from sorted edge_row ----
__global__ void k_rowptr(const int* __restrict__ erow, int* __restrict__ row_ptr) {
    int e = blockIdx.x * 256 + threadIdx.x;
    if (e >= N_EDGES) return;
    int r = erow[e];
    int rprev = (e == 0) ? -1 : erow[e - 1];
    for (int rr = rprev + 1; rr <= r; ++rr) row_ptr[rr] = e;
    if (e == N_EDGES - 1) {
        for (int rr = r + 1; rr <= N_NODES; ++rr) row_ptr[rr] = N_EDGES;
    }
}

// ---- Kernel 2: H = tanh(A @ W) in bf16. 128x128 tile, 4 waves (2x2), no LDS ----
__global__ __launch_bounds__(256) void k_gemm(const float* __restrict__ A,
                                              const unsigned short* __restrict__ Wt,
                                              unsigned short* __restrict__ H,
                                              const int* __restrict__ activep) {
    const int tid  = threadIdx.x;
    const int lane = tid & 63;
    const int wid  = tid >> 6;
    const int wr   = wid >> 1;   // 0..1 row-half
    const int wc   = wid & 1;    // 0..1 col-half
    const int brow = blockIdx.x * 128;
    const int l15  = lane & 15;
    const int lk   = (lane >> 4) * 8;  // k-offset of this lane's 8 elems

    f32x4 acc[4][4] = {};

    for (int k0 = 0; k0 < IN_F; k0 += 32) {
        bf16x8 a[4], b[4];
        #pragma unroll
        for (int i = 0; i < 4; ++i) {
            int row = brow + wr * 64 + i * 16 + l15;
            if (row > N_NODES - 1) row = N_NODES - 1;   // clamp OOB reads
            const float* p = A + (long)row * IN_F + k0 + lk;
            float4 f0 = *(const float4*)(p);
            float4 f1 = *(const float4*)(p + 4);
            bf16x8 v;
            v[0] = (short)f2bf(f0.x); v[1] = (short)f2bf(f0.y);
            v[2] = (short)f2bf(f0.z); v[3] = (short)f2bf(f0.w);
            v[4] = (short)f2bf(f1.x); v[5] = (short)f2bf(f1.y);
            v[6] = (short)f2bf(f1.z); v[7] = (short)f2bf(f1.w);
            a[i] = v;
        }
        #pragma unroll
        for (int n = 0; n < 4; ++n) {
            int col = wc * 64 + n * 16 + l15;
            b[n] = *(const bf16x8*)(Wt + col * IN_F + k0 + lk);
        }
        #pragma unroll
        for (int i = 0; i < 4; ++i)
            #pragma unroll
            for (int n = 0; n < 4; ++n)
                acc[i][n] = __builtin_amdgcn_mfma_f32_16x16x32_bf16(a[i], b[n], acc[i][n], 0, 0, 0);
    }

    const int act = *activep;
    // C/D layout: col = lane&15, row = (lane>>4)*4 + reg   [m89-verified]
    #pragma unroll
    for (int i = 0; i < 4; ++i) {
        #pragma unroll
        for (int n = 0; n < 4; ++n) {
            #pragma unroll
            for (int r = 0; r < 4; ++r) {
                int row = brow + wr * 64 + i * 16 + (lane >> 4) * 4 + r;
                int col = wc * 64 + n * 16 + l15;
                if (row < N_NODES) {
                    float v = acc[i][n][r];
                    if (act) v = tanhf(v);
                    H[(long)row * OUT_F + col] = f2bf(v);
                }
            }
        }
    }
}

// ---- Kernel 3: SpMM. One wave per output row; lane owns 2 of 128 cols ----
__global__ __launch_bounds__(256) void k_spmm(const int* __restrict__ row_ptr,
                                              const int* __restrict__ ecol,
                                              const float* __restrict__ eval,
                                              const unsigned int* __restrict__ h32, // bf16x2 per dword
                                              float* __restrict__ out) {
    const int lane = threadIdx.x & 63;
    const int w    = threadIdx.x >> 6;
    const int r    = blockIdx.x * 4 + w;
    if (r >= N_NODES) return;

    const int s = row_ptr[r];
    const int e = row_ptr[r + 1];

    float ax = 0.f, ay = 0.f;
    for (int base = s; base < e; base += 64) {
        const int idx = base + lane;
        int   cc = 0;
        float vv = 0.f;
        if (idx < e) { cc = ecol[idx]; vv = eval[idx]; }
        const int n = min(64, e - base);
        for (int j = 0; j < n; ++j) {
            const int   cj = __shfl(cc, j);
            const float vj = __shfl(vv, j);
            const unsigned int hv = h32[cj * 64 + lane];
            const float hx = __uint_as_float(hv << 16);
            const float hy = __uint_as_float(hv & 0xffff0000u);
            ax = fmaf(vj, hx, ax);
            ay = fmaf(vj, hy, ay);
        }
    }
    float2 res; res.x = ax; res.y = ay;
    ((float2*)out)[(long)r * 64 + lane] = res;
}

extern "C" void kernel_launch(void* const* d_in, const int* in_sizes, int n_in,
                              void* d_out, int out_size, void* d_ws, size_t ws_size,
                              hipStream_t stream) {
    const float* features = (const float*)d_in[0];
    const float* weight   = (const float*)d_in[1];
    const int*   erow     = (const int*)d_in[2];
    const int*   ecol     = (const int*)d_in[3];
    const float* evalp    = (const float*)d_in[4];
    const int*   activep  = (const int*)d_in[5];
    float* out = (float*)d_out;

    char* ws = (char*)d_ws;
    unsigned short* H  = (unsigned short*)ws;                         // 25,600,000 B
    unsigned short* Wt = (unsigned short*)(ws + 25600000);            //     65,536 B
    int* row_ptr       = (int*)(ws + 25600000 + 65536);               //    400,004 B

    k_wt    <<<128, 256, 0, stream>>>(weight, Wt);
    k_rowptr<<<(N_EDGES + 255) / 256, 256, 0, stream>>>(erow, row_ptr);
    k_gemm  <<<(N_NODES + 127) / 128, 256, 0, stream>>>(features, Wt, H, activep);
    k_spmm  <<<(N_NODES + 3) / 4, 256, 0, stream>>>(row_ptr, ecol, evalp,
                                                    (const unsigned int*)H, out);
}

// Round 2
// 186.559 us; speedup vs baseline: 1.3819x; 1.3819x over previous
//
#include <hip/hip_runtime.h>
#include <hip/hip_bf16.h>

#define N_NODES 100000
#define N_EDGES 3200000
#define IN_F 256
#define OUT_F 128

typedef __attribute__((ext_vector_type(8))) short bf16x8;
typedef __attribute__((ext_vector_type(4))) float f32x4;

__device__ __forceinline__ unsigned short f2bf(float f) {
    unsigned int u = __float_as_uint(f);
    u += 0x7fffu + ((u >> 16) & 1u);   // round-to-nearest-even
    return (unsigned short)(u >> 16);
}

// ---- Kernel 0: W [256][128] f32 -> Wt [128][256] bf16 (transpose+convert) ----
__global__ void k_wt(const float* __restrict__ W, unsigned short* __restrict__ Wt) {
    int idx = blockIdx.x * 256 + threadIdx.x;
    if (idx >= IN_F * OUT_F) return;
    int k = idx >> 7;          // 0..255
    int c = idx & 127;         // 0..127
    Wt[c * IN_F + k] = f2bf(W[idx]);
}

// ---- Kernel 1: CSR row_ptr from sorted edge_row ----
__global__ void k_rowptr(const int* __restrict__ erow, int* __restrict__ row_ptr) {
    int e = blockIdx.x * 256 + threadIdx.x;
    if (e >= N_EDGES) return;
    int r = erow[e];
    int rprev = (e == 0) ? -1 : erow[e - 1];
    for (int rr = rprev + 1; rr <= r; ++rr) row_ptr[rr] = e;
    if (e == N_EDGES - 1) {
        for (int rr = r + 1; rr <= N_NODES; ++rr) row_ptr[rr] = N_EDGES;
    }
}

// ---- Kernel 2: H = tanh(A @ W) in bf16. 128x128 tile, 4 waves (2x2), no LDS ----
__global__ __launch_bounds__(256) void k_gemm(const float* __restrict__ A,
                                              const unsigned short* __restrict__ Wt,
                                              unsigned short* __restrict__ H,
                                              const int* __restrict__ activep) {
    const int tid  = threadIdx.x;
    const int lane = tid & 63;
    const int wid  = tid >> 6;
    const int wr   = wid >> 1;   // 0..1 row-half
    const int wc   = wid & 1;    // 0..1 col-half
    const int brow = blockIdx.x * 128;
    const int l15  = lane & 15;
    const int lk   = (lane >> 4) * 8;  // k-offset of this lane's 8 elems

    f32x4 acc[4][4] = {};

    for (int k0 = 0; k0 < IN_F; k0 += 32) {
        bf16x8 a[4], b[4];
        #pragma unroll
        for (int i = 0; i < 4; ++i) {
            int row = brow + wr * 64 + i * 16 + l15;
            if (row > N_NODES - 1) row = N_NODES - 1;   // clamp OOB reads
            const float* p = A + (long)row * IN_F + k0 + lk;
            float4 f0 = *(const float4*)(p);
            float4 f1 = *(const float4*)(p + 4);
            bf16x8 v;
            v[0] = (short)f2bf(f0.x); v[1] = (short)f2bf(f0.y);
            v[2] = (short)f2bf(f0.z); v[3] = (short)f2bf(f0.w);
            v[4] = (short)f2bf(f1.x); v[5] = (short)f2bf(f1.y);
            v[6] = (short)f2bf(f1.z); v[7] = (short)f2bf(f1.w);
            a[i] = v;
        }
        #pragma unroll
        for (int n = 0; n < 4; ++n) {
            int col = wc * 64 + n * 16 + l15;
            b[n] = *(const bf16x8*)(Wt + col * IN_F + k0 + lk);
        }
        #pragma unroll
        for (int i = 0; i < 4; ++i)
            #pragma unroll
            for (int n = 0; n < 4; ++n)
                acc[i][n] = __builtin_amdgcn_mfma_f32_16x16x32_bf16(a[i], b[n], acc[i][n], 0, 0, 0);
    }

    const int act = *activep;
    // C/D layout: col = lane&15, row = (lane>>4)*4 + reg   [m89-verified]
    #pragma unroll
    for (int i = 0; i < 4; ++i) {
        #pragma unroll
        for (int n = 0; n < 4; ++n) {
            #pragma unroll
            for (int r = 0; r < 4; ++r) {
                int row = brow + wr * 64 + i * 16 + (lane >> 4) * 4 + r;
                int col = wc * 64 + n * 16 + l15;
                if (row < N_NODES) {
                    float v = acc[i][n][r];
                    if (act) v = tanhf(v);
                    H[(long)row * OUT_F + col] = f2bf(v);
                }
            }
        }
    }
}

// ---- Kernel 3: SpMM. One wave per row; lane owns 2 of 128 cols.
//      Edges fetched as wave-uniform broadcast loads (no shfl), 8 edges/iter,
//      gathers batched for ILP. ----
__global__ __launch_bounds__(256) void k_spmm(const int* __restrict__ row_ptr,
                                              const int* __restrict__ ecol,
                                              const float* __restrict__ eval,
                                              const unsigned int* __restrict__ h32, // bf16x2 per dword
                                              float* __restrict__ out) {
    const int lane = threadIdx.x & 63;
    const int w    = threadIdx.x >> 6;
    const int r    = blockIdx.x * 4 + w;
    if (r >= N_NODES) return;

    const int s = __builtin_amdgcn_readfirstlane(row_ptr[r]);
    const int e = __builtin_amdgcn_readfirstlane(row_ptr[r + 1]);

    float ax = 0.f, ay = 0.f;
    int j = s;

    // head: align j to 4 so int4/float4 edge loads are 16B-aligned
    const int head = min(e, (s + 3) & ~3);
    for (; j < head; ++j) {
        const int   c = ecol[j];
        const float v = eval[j];
        const unsigned int hv = h32[c * 64 + lane];
        ax = fmaf(v, __uint_as_float(hv << 16), ax);
        ay = fmaf(v, __uint_as_float(hv & 0xffff0000u), ay);
    }

    // main: 8 edges per iteration; all gathers issued before FMAs
    for (; j + 8 <= e; j += 8) {
        const int4   ca = *(const int4*)(ecol + j);
        const int4   cb = *(const int4*)(ecol + j + 4);
        const float4 va = *(const float4*)(eval + j);
        const float4 vb = *(const float4*)(eval + j + 4);

        const unsigned int h0 = h32[ca.x * 64 + lane];
        const unsigned int h1 = h32[ca.y * 64 + lane];
        const unsigned int h2 = h32[ca.z * 64 + lane];
        const unsigned int h3 = h32[ca.w * 64 + lane];
        const unsigned int h4 = h32[cb.x * 64 + lane];
        const unsigned int h5 = h32[cb.y * 64 + lane];
        const unsigned int h6 = h32[cb.z * 64 + lane];
        const unsigned int h7 = h32[cb.w * 64 + lane];

        ax = fmaf(va.x, __uint_as_float(h0 << 16), ax);
        ay = fmaf(va.x, __uint_as_float(h0 & 0xffff0000u), ay);
        ax = fmaf(va.y, __uint_as_float(h1 << 16), ax);
        ay = fmaf(va.y, __uint_as_float(h1 & 0xffff0000u), ay);
        ax = fmaf(va.z, __uint_as_float(h2 << 16), ax);
        ay = fmaf(va.z, __uint_as_float(h2 & 0xffff0000u), ay);
        ax = fmaf(va.w, __uint_as_float(h3 << 16), ax);
        ay = fmaf(va.w, __uint_as_float(h3 & 0xffff0000u), ay);
        ax = fmaf(vb.x, __uint_as_float(h4 << 16), ax);
        ay = fmaf(vb.x, __uint_as_float(h4 & 0xffff0000u), ay);
        ax = fmaf(vb.y, __uint_as_float(h5 << 16), ax);
        ay = fmaf(vb.y, __uint_as_float(h5 & 0xffff0000u), ay);
        ax = fmaf(vb.z, __uint_as_float(h6 << 16), ax);
        ay = fmaf(vb.z, __uint_as_float(h6 & 0xffff0000u), ay);
        ax = fmaf(vb.w, __uint_as_float(h7 << 16), ax);
        ay = fmaf(vb.w, __uint_as_float(h7 & 0xffff0000u), ay);
    }

    // tail
    for (; j < e; ++j) {
        const int   c = ecol[j];
        const float v = eval[j];
        const unsigned int hv = h32[c * 64 + lane];
        ax = fmaf(v, __uint_as_float(hv << 16), ax);
        ay = fmaf(v, __uint_as_float(hv & 0xffff0000u), ay);
    }

    float2 res; res.x = ax; res.y = ay;
    ((float2*)out)[(long)r * 64 + lane] = res;
}

extern "C" void kernel_launch(void* const* d_in, const int* in_sizes, int n_in,
                              void* d_out, int out_size, void* d_ws, size_t ws_size,
                              hipStream_t stream) {
    const float* features = (const float*)d_in[0];
    const float* weight   = (const float*)d_in[1];
    const int*   erow     = (const int*)d_in[2];
    const int*   ecol     = (const int*)d_in[3];
    const float* evalp    = (const float*)d_in[4];
    const int*   activep  = (const int*)d_in[5];
    float* out = (float*)d_out;

    char* ws = (char*)d_ws;
    unsigned short* H  = (unsigned short*)ws;                         // 25,600,000 B
    unsigned short* Wt = (unsigned short*)(ws + 25600000);            //     65,536 B
    int* row_ptr       = (int*)(ws + 25600000 + 65536);               //    400,004 B

    k_wt    <<<128, 256, 0, stream>>>(weight, Wt);
    k_rowptr<<<(N_EDGES + 255) / 256, 256, 0, stream>>>(erow, row_ptr);
    k_gemm  <<<(N_NODES + 127) / 128, 256, 0, stream>>>(features, Wt, H, activep);
    k_spmm  <<<(N_NODES + 3) / 4, 256, 0, stream>>>(row_ptr, ecol, evalp,
                                                    (const unsigned int*)H, out);
}

// Round 3
// 183.080 us; speedup vs baseline: 1.4081x; 1.0190x over previous
//
#include <hip/hip_runtime.h>
#include <hip/hip_bf16.h>

#define N_NODES 100000
#define N_EDGES 3200000
#define IN_F 256
#define OUT_F 128

typedef __attribute__((ext_vector_type(8))) short bf16x8;
typedef __attribute__((ext_vector_type(4))) float f32x4;

__device__ __forceinline__ unsigned short f2bf(float f) {
    unsigned int u = __float_as_uint(f);
    u += 0x7fffu + ((u >> 16) & 1u);   // round-to-nearest-even
    return (unsigned short)(u >> 16);
}

// ---- Kernel 0: W [256][128] f32 -> Wt [128][256] bf16 (transpose+convert) ----
__global__ void k_wt(const float* __restrict__ W, unsigned short* __restrict__ Wt) {
    int idx = blockIdx.x * 256 + threadIdx.x;
    if (idx >= IN_F * OUT_F) return;
    int k = idx >> 7;          // 0..255
    int c = idx & 127;         // 0..127
    Wt[c * IN_F + k] = f2bf(W[idx]);
}

// ---- Kernel 1: CSR row_ptr from sorted edge_row ----
__global__ void k_rowptr(const int* __restrict__ erow, int* __restrict__ row_ptr) {
    int e = blockIdx.x * 256 + threadIdx.x;
    if (e >= N_EDGES) return;
    int r = erow[e];
    int rprev = (e == 0) ? -1 : erow[e - 1];
    for (int rr = rprev + 1; rr <= r; ++rr) row_ptr[rr] = e;
    if (e == N_EDGES - 1) {
        for (int rr = r + 1; rr <= N_NODES; ++rr) row_ptr[rr] = N_EDGES;
    }
}

// ---- Kernel 2: H = tanh(A @ W) in bf16. 128x128 tile, 4 waves (2x2), no LDS ----
__global__ __launch_bounds__(256) void k_gemm(const float* __restrict__ A,
                                              const unsigned short* __restrict__ Wt,
                                              unsigned short* __restrict__ H,
                                              const int* __restrict__ activep) {
    const int tid  = threadIdx.x;
    const int lane = tid & 63;
    const int wid  = tid >> 6;
    const int wr   = wid >> 1;   // 0..1 row-half
    const int wc   = wid & 1;    // 0..1 col-half
    const int brow = blockIdx.x * 128;
    const int l15  = lane & 15;
    const int lk   = (lane >> 4) * 8;  // k-offset of this lane's 8 elems

    f32x4 acc[4][4] = {};

    for (int k0 = 0; k0 < IN_F; k0 += 32) {
        bf16x8 a[4], b[4];
        #pragma unroll
        for (int i = 0; i < 4; ++i) {
            int row = brow + wr * 64 + i * 16 + l15;
            if (row > N_NODES - 1) row = N_NODES - 1;   // clamp OOB reads
            const float* p = A + (long)row * IN_F + k0 + lk;
            float4 f0 = *(const float4*)(p);
            float4 f1 = *(const float4*)(p + 4);
            bf16x8 v;
            v[0] = (short)f2bf(f0.x); v[1] = (short)f2bf(f0.y);
            v[2] = (short)f2bf(f0.z); v[3] = (short)f2bf(f0.w);
            v[4] = (short)f2bf(f1.x); v[5] = (short)f2bf(f1.y);
            v[6] = (short)f2bf(f1.z); v[7] = (short)f2bf(f1.w);
            a[i] = v;
        }
        #pragma unroll
        for (int n = 0; n < 4; ++n) {
            int col = wc * 64 + n * 16 + l15;
            b[n] = *(const bf16x8*)(Wt + col * IN_F + k0 + lk);
        }
        #pragma unroll
        for (int i = 0; i < 4; ++i)
            #pragma unroll
            for (int n = 0; n < 4; ++n)
                acc[i][n] = __builtin_amdgcn_mfma_f32_16x16x32_bf16(a[i], b[n], acc[i][n], 0, 0, 0);
    }

    const int act = *activep;
    // C/D layout: col = lane&15, row = (lane>>4)*4 + reg   [m89-verified]
    #pragma unroll
    for (int i = 0; i < 4; ++i) {
        #pragma unroll
        for (int n = 0; n < 4; ++n) {
            #pragma unroll
            for (int r = 0; r < 4; ++r) {
                int row = brow + wr * 64 + i * 16 + (lane >> 4) * 4 + r;
                int col = wc * 64 + n * 16 + l15;
                if (row < N_NODES) {
                    float v = acc[i][n][r];
                    if (act) v = tanhf(v);
                    H[(long)row * OUT_F + col] = f2bf(v);
                }
            }
        }
    }
}

// ---- Kernel 3: SpMM. One wave per row. 16 lanes cover one edge's 256B row,
//      so one uint4 gather instruction covers 4 edges (1KB in flight each).
//      16 edges per loop iter = 4 gather instrs + 8 small edge loads.
//      Cross edge-slot reduce via shfl_xor(16/32) butterfly at row end. ----
__global__ __launch_bounds__(256) void k_spmm(const int* __restrict__ row_ptr,
                                              const int* __restrict__ ecol,
                                              const float* __restrict__ eval,
                                              const unsigned int* __restrict__ h32, // bf16x2 per dword
                                              float* __restrict__ out) {
    const int lane = threadIdx.x & 63;
    const int w    = threadIdx.x >> 6;
    const int r    = blockIdx.x * 4 + w;
    if (r >= N_NODES) return;

    const int q  = lane >> 4;         // edge slot 0..3 within wave
    const int dq = (lane & 15) * 4;   // dword offset within h row (0..60)

    const int s = __builtin_amdgcn_readfirstlane(row_ptr[r]);
    const int e = __builtin_amdgcn_readfirstlane(row_ptr[r + 1]);

    const unsigned int* hq = h32 + dq;

    float f0 = 0.f, f1 = 0.f, f2 = 0.f, f3 = 0.f;
    float f4 = 0.f, f5 = 0.f, f6 = 0.f, f7 = 0.f;

    for (int j = s; j < e; j += 16) {
        int   cc[4];
        float vv[4];
        #pragma unroll
        for (int u = 0; u < 4; ++u) {
            const int want = j + u * 4 + q;
            const int idx  = min(want, e - 1);     // always in-bounds (e>s here)
            cc[u] = ecol[idx];
            vv[u] = (want < e) ? eval[idx] : 0.f;  // predicate via value, not branch
        }
        uint4 g[4];
        #pragma unroll
        for (int u = 0; u < 4; ++u)
            g[u] = *(const uint4*)(hq + (((unsigned)cc[u]) << 6));
        #pragma unroll
        for (int u = 0; u < 4; ++u) {
            const float v = vv[u];
            f0 = fmaf(v, __uint_as_float(g[u].x << 16), f0);
            f1 = fmaf(v, __uint_as_float(g[u].x & 0xffff0000u), f1);
            f2 = fmaf(v, __uint_as_float(g[u].y << 16), f2);
            f3 = fmaf(v, __uint_as_float(g[u].y & 0xffff0000u), f3);
            f4 = fmaf(v, __uint_as_float(g[u].z << 16), f4);
            f5 = fmaf(v, __uint_as_float(g[u].z & 0xffff0000u), f5);
            f6 = fmaf(v, __uint_as_float(g[u].w << 16), f6);
            f7 = fmaf(v, __uint_as_float(g[u].w & 0xffff0000u), f7);
        }
    }

    // reduce the 4 edge slots: lanes l, l+16, l+32, l+48 hold the same columns
    #pragma unroll
    for (int mask = 16; mask <= 32; mask <<= 1) {
        f0 += __shfl_xor(f0, mask);
        f1 += __shfl_xor(f1, mask);
        f2 += __shfl_xor(f2, mask);
        f3 += __shfl_xor(f3, mask);
        f4 += __shfl_xor(f4, mask);
        f5 += __shfl_xor(f5, mask);
        f6 += __shfl_xor(f6, mask);
        f7 += __shfl_xor(f7, mask);
    }

    if (q == 0) {
        float* dst = out + (long)r * OUT_F + dq * 2;  // dq*2 = (lane&15)*8 cols
        float4 o0; o0.x = f0; o0.y = f1; o0.z = f2; o0.w = f3;
        float4 o1; o1.x = f4; o1.y = f5; o1.z = f6; o1.w = f7;
        *(float4*)dst       = o0;
        *(float4*)(dst + 4) = o1;
    }
}

extern "C" void kernel_launch(void* const* d_in, const int* in_sizes, int n_in,
                              void* d_out, int out_size, void* d_ws, size_t ws_size,
                              hipStream_t stream) {
    const float* features = (const float*)d_in[0];
    const float* weight   = (const float*)d_in[1];
    const int*   erow     = (const int*)d_in[2];
    const int*   ecol     = (const int*)d_in[3];
    const float* evalp    = (const float*)d_in[4];
    const int*   activep  = (const int*)d_in[5];
    float* out = (float*)d_out;

    char* ws = (char*)d_ws;
    unsigned short* H  = (unsigned short*)ws;                         // 25,600,000 B
    unsigned short* Wt = (unsigned short*)(ws + 25600000);            //     65,536 B
    int* row_ptr       = (int*)(ws + 25600000 + 65536);               //    400,004 B

    k_wt    <<<128, 256, 0, stream>>>(weight, Wt);
    k_rowptr<<<(N_EDGES + 255) / 256, 256, 0, stream>>>(erow, row_ptr);
    k_gemm  <<<(N_NODES + 127) / 128, 256, 0, stream>>>(features, Wt, H, activep);
    k_spmm  <<<(N_NODES + 3) / 4, 256, 0, stream>>>(row_ptr, ecol, evalp,
                                                    (const unsigned int*)H, out);
}